// Round 5
// baseline (296.234 us; speedup 1.0000x reference)
//
#include <hip/hip_runtime.h>

#define SCALE 0.17677669529663687f

typedef __attribute__((ext_vector_type(8))) short bf16x8;
typedef __attribute__((ext_vector_type(4))) short bf16x4;
typedef __attribute__((ext_vector_type(4))) float f32x4;

__device__ inline short cvt_bf16(float f) {          // RNE (prep: weights/q)
    union { float f; unsigned u; } v; v.f = f;
    unsigned r = v.u + 0x7fffu + ((v.u >> 16) & 1u);
    return (short)(r >> 16);
}
__device__ inline short cvt_bf16_fast(float f) {     // round-up-ties, 2 ops
    union { float f; unsigned u; } v; v.f = f;
    return (short)((v.u + 0x8000u) >> 16);
}
__device__ inline unsigned pack_bf16x2(float f0, float f1) {
    union { float f; unsigned u; } a, b; a.f = f0; b.f = f1;
    return __builtin_amdgcn_perm(b.u + 0x8000u, a.u + 0x8000u, 0x07060302u);
}

#if __has_builtin(__builtin_amdgcn_mfma_f32_16x16x16bf16_1k)
__device__ inline f32x4 mfma16x16(bf16x4 a, bf16x4 b, f32x4 c) {
    return __builtin_amdgcn_mfma_f32_16x16x16bf16_1k(a, b, c, 0, 0, 0);
}
#else
__device__ inline f32x4 mfma16x16(bf16x4 a, bf16x4 b, f32x4 c) {
    asm("v_mfma_f32_16x16x16_bf16 %0, %1, %2, %0" : "+v"(c) : "v"(a), "v"(b));
    return c;
}
#endif

// ws layout (short elements):
//   [0, 32768)        W_kv^T  bf16 [256][128]
//   [32768, 49152)    W_proj^T bf16 [128][128]
//   [49152, 450560)   q bf16 * SCALE, [64 img][4 h][49 n][32 d]
//   short 450560..    bias fp32 [4 h][49 i][64 jpad]
#define WS_WPT  32768
#define WS_QW   49152
#define WS_BIAS 450560

__global__ void prep_kernel(const float* __restrict__ qg,
                            const float* __restrict__ rbt,
                            const float* __restrict__ wkv,
                            const float* __restrict__ wpj,
                            const int*   __restrict__ ridx,
                            short* __restrict__ ws) {
    int i = blockIdx.x * 256 + threadIdx.x;
    if (i < 32768) {                       // W_kv^T
        int c = i >> 7, k = i & 127;
        ws[i] = cvt_bf16(wkv[k * 256 + c]);
        return;
    }
    i -= 32768;
    if (i < 16384) {                       // W_proj^T
        int c = i >> 7, k = i & 127;
        ws[WS_WPT + i] = cvt_bf16(wpj[k * 128 + c]);
        return;
    }
    i -= 16384;
    if (i < 100352) {                      // q * SCALE, 4 elems/thread
        float4 q4 = *(const float4*)(qg + (long)i * 4);
        unsigned lo = (unsigned)(unsigned short)cvt_bf16(q4.x * SCALE) |
                      ((unsigned)(unsigned short)cvt_bf16(q4.y * SCALE) << 16);
        unsigned hi = (unsigned)(unsigned short)cvt_bf16(q4.z * SCALE) |
                      ((unsigned)(unsigned short)cvt_bf16(q4.w * SCALE) << 16);
        uint2 u; u.x = lo; u.y = hi;
        *(uint2*)(ws + WS_QW + (long)i * 4) = u;
        return;
    }
    i -= 100352;
    if (i < 12544) {                       // bias padded [h][i][64]
        int h = i / 3136, rem = i % 3136, ir = rem >> 6, j = rem & 63;
        float* bias = (float*)(ws + WS_BIAS);
        bias[i] = (j < 49) ? rbt[ridx[ir * 49 + j] * 4 + h] : 0.f;
    }
}

// LDS (shorts), 29008 B. Regions now DISJOINT (no time-multiplexing):
//  K  @0:    [4 heads][49 rows x 40]  -- own-wave written & read (no barrier)
//  os @7840: [49][136]                -- O scratch for stage 4 (1 barrier before reads)
// x never touches LDS: each wave loads the full x tile directly into MFMA
// A-fragments (xfrag[4][4], 64 VGPR; coalesced 32B/lane global reads), reused
// across the K-pass and V-pass. This removes stage 0 + barriers 1 & 2, and
// lets x/W_kv/q/bias loads all issue concurrently at kernel start.
// V and P never touch LDS (reg-resident 16x16x16 B-frag / A-frag layouts).
// launch_bounds min-waves: 4 (rounds 1 & 3 proved the 5-wave 96-reg budget
// force-spills: WRITE_SIZE 110->277..311 MB scratch, dur 136->165..184 us).
#define KSLOT   1960
#define OOFF    7840
#define SMEM_SZ 14504

__global__ __launch_bounds__(256, 4) void win_attn_kernel(
        const float* __restrict__ x,
        const short* __restrict__ ws,
        const float* __restrict__ bkv,
        const float* __restrict__ bpj,
        float* __restrict__ out) {
    const int b    = blockIdx.x;
    const int img  = b >> 6;
    const int tid  = threadIdx.x;
    const int w    = tid >> 6;
    const int lane = tid & 63;
    const int quad = lane >> 4;
    const int l16  = lane & 15;

    const short* wkvt  = ws;
    const short* wpt   = ws + WS_WPT;
    const short* qw    = ws + WS_QW;
    const float* biasb = (const float*)(ws + WS_BIAS);

    __shared__ __align__(16) short smem[SMEM_SZ];
    short* os = smem + OOFF;

    const f32x4 fzero = {0.f, 0.f, 0.f, 0.f};
    const int h = w;

    // ---------------- Stage 0': x -> registers as A-fragments (per wave) ----------------
    // frag (kk,mi): lane holds x[tok][kk*32+quad*8 .. +8], tok = min(mi*16+l16, 48).
    // quads tile 128B row segments -> fully coalesced; 4 waves re-read via L1/L2.
    const float* xb = x + (long)b * 49 * 128;
    const float* xrow[4];
    #pragma unroll
    for (int mi = 0; mi < 4; ++mi) {
        int tok = mi * 16 + l16; if (tok > 48) tok = 48;
        xrow[mi] = xb + tok * 128 + quad * 8;
    }
    bf16x8 xfrag[4][4];                    // [kk][mi]
    #pragma unroll
    for (int kk = 0; kk < 4; ++kk)
        #pragma unroll
        for (int mi = 0; mi < 4; ++mi) {
            const float* p = xrow[mi] + kk * 32;
            float4 a = *(const float4*)p;
            float4 c = *(const float4*)(p + 4);
            union { uint4 u; bf16x8 v; } pk;
            pk.u.x = pack_bf16x2(a.x, a.y);
            pk.u.y = pack_bf16x2(a.z, a.w);
            pk.u.z = pack_bf16x2(c.x, c.y);
            pk.u.w = pack_bf16x2(c.z, c.w);
            xfrag[kk][mi] = pk.v;
        }

    // ---------------- Stage 1A: K = x @ W_kv[:, h*32 .. h*32+32) ----------------
    short* ksl = smem + h * KSLOT;
    {
        f32x4 acck[2][4];
        #pragma unroll
        for (int nt = 0; nt < 2; ++nt)
            #pragma unroll
            for (int mi = 0; mi < 4; ++mi) acck[nt][mi] = fzero;

        #pragma unroll
        for (int kk = 0; kk < 4; ++kk) {
            bf16x8 bfr[2];
            #pragma unroll
            for (int nt = 0; nt < 2; ++nt)
                bfr[nt] = *(const bf16x8*)(wkvt + (h * 32 + nt * 16 + l16) * 128 + kk * 32 + quad * 8);
            #pragma unroll
            for (int mi = 0; mi < 4; ++mi)
                #pragma unroll
                for (int nt = 0; nt < 2; ++nt)
                    acck[nt][mi] = __builtin_amdgcn_mfma_f32_16x16x32_bf16(xfrag[kk][mi], bfr[nt], acck[nt][mi], 0, 0, 0);
        }
        // K -> LDS own-head slot (same-wave RW, disjoint region: no barrier)
        #pragma unroll
        for (int nt = 0; nt < 2; ++nt) {
            const int d = nt * 16 + l16;
            const float bv = bkv[h * 32 + d];
            short* kdst = ksl + d;
            #pragma unroll
            for (int mi = 0; mi < 4; ++mi)
                #pragma unroll
                for (int r = 0; r < 4; ++r) {
                    int tok = mi * 16 + quad * 4 + r;
                    if (tok < 49) kdst[tok * 40] = cvt_bf16_fast(acck[nt][mi][r] + bv);
                }
        }
    }

    // ---------------- Stage 1B: V = x @ W_kv[:, 128+h*32 ..) -> registers ----------------
    // acc layout (row=16*kt+4*quad+r, col=l16) == 16x16x16 MFMA B-fragment
    bf16x4 vfrag[2][4];                    // [nv][kt]
    {
        f32x4 accv[2][4];
        #pragma unroll
        for (int nv = 0; nv < 2; ++nv)
            #pragma unroll
            for (int mi = 0; mi < 4; ++mi) accv[nv][mi] = fzero;

        #pragma unroll
        for (int kk = 0; kk < 4; ++kk) {
            bf16x8 bfr[2];
            #pragma unroll
            for (int nv = 0; nv < 2; ++nv)
                bfr[nv] = *(const bf16x8*)(wkvt + (128 + h * 32 + nv * 16 + l16) * 128 + kk * 32 + quad * 8);
            #pragma unroll
            for (int mi = 0; mi < 4; ++mi)
                #pragma unroll
                for (int nv = 0; nv < 2; ++nv)
                    accv[nv][mi] = __builtin_amdgcn_mfma_f32_16x16x32_bf16(xfrag[kk][mi], bfr[nv], accv[nv][mi], 0, 0, 0);
        }
        #pragma unroll
        for (int nv = 0; nv < 2; ++nv) {
            const float bv = bkv[128 + h * 32 + nv * 16 + l16];
            #pragma unroll
            for (int kt = 0; kt < 4; ++kt) {
                union { unsigned u[2]; bf16x4 v; } pk;
                pk.u[0] = pack_bf16x2(accv[nv][kt][0] + bv, accv[nv][kt][1] + bv);
                pk.u[1] = pack_bf16x2(accv[nv][kt][2] + bv, accv[nv][kt][3] + bv);
                vfrag[nv][kt] = pk.v;
            }
        }
    }

    // ---------------- Stage 2+3 fused: St = K@q^T, softmax, O += P@V (in-register) ----------------
    const short* qh = qw + (long)(img * 4 + h) * 49 * 32;
    f32x4 oacc[4][2];                      // [mo=ni][nv]
    #pragma unroll
    for (int mo = 0; mo < 4; ++mo)
        #pragma unroll
        for (int nv = 0; nv < 2; ++nv) oacc[mo][nv] = fzero;

    #pragma unroll
    for (int ni = 0; ni < 4; ++ni) {
        int ic = ni * 16 + l16; if (ic > 48) ic = 48;
        bf16x8 qf = *(const bf16x8*)(qh + ic * 32 + quad * 8);
        f32x4 sacc[4] = {fzero, fzero, fzero, fzero};
        #pragma unroll
        for (int mi = 0; mi < 4; ++mi) {
            int kr = mi * 16 + l16; if (kr > 48) kr = 48;
            bf16x8 kf = *(const bf16x8*)(ksl + kr * 40 + quad * 8);
            sacc[mi] = __builtin_amdgcn_mfma_f32_16x16x32_bf16(kf, qf, sacc[mi], 0, 0, 0);
        }
        // bias + j-mask (in place)
        const float* bp = biasb + (h * 49 + ic) * 64;
        #pragma unroll
        for (int mi = 0; mi < 4; ++mi) {
            float4 b4 = *(const float4*)(bp + mi * 16 + quad * 4);
            float bb[4] = {b4.x, b4.y, b4.z, b4.w};
            #pragma unroll
            for (int r = 0; r < 4; ++r) {
                int j = mi * 16 + quad * 4 + r;
                sacc[mi][r] = (j < 49) ? (sacc[mi][r] + bb[r]) : -3.0e38f;
            }
        }
        // softmax over j (16 per lane x 4 quads)
        float m = -3.0e38f;
        #pragma unroll
        for (int mi = 0; mi < 4; ++mi)
            #pragma unroll
            for (int r = 0; r < 4; ++r) m = fmaxf(m, sacc[mi][r]);
        m = fmaxf(m, __shfl_xor(m, 16, 64));
        m = fmaxf(m, __shfl_xor(m, 32, 64));
        float sum = 0.f;
        #pragma unroll
        for (int mi = 0; mi < 4; ++mi)
            #pragma unroll
            for (int r = 0; r < 4; ++r) {
                float e = __expf(sacc[mi][r] - m);
                sacc[mi][r] = e; sum += e;
            }
        sum += __shfl_xor(sum, 16, 64);
        sum += __shfl_xor(sum, 32, 64);
        float inv = 1.0f / sum;
        // P row is lane-local in 16x16x16 A-frag layout (k = quad*4+e): PV directly
        #pragma unroll
        for (int kt = 0; kt < 4; ++kt) {
            union { unsigned u[2]; bf16x4 v; } pk;
            pk.u[0] = pack_bf16x2(sacc[kt][0] * inv, sacc[kt][1] * inv);
            pk.u[1] = pack_bf16x2(sacc[kt][2] * inv, sacc[kt][3] * inv);
            #pragma unroll
            for (int nv = 0; nv < 2; ++nv)
                oacc[ni][nv] = mfma16x16(pk.v, vfrag[nv][kt], oacc[ni][nv]);
        }
    }

    // ---------------- O -> LDS (own 32 cols), then the ONLY barrier ----------------
    #pragma unroll
    for (int mo = 0; mo < 4; ++mo)
        #pragma unroll
        for (int nv = 0; nv < 2; ++nv)
            #pragma unroll
            for (int r = 0; r < 4; ++r) {
                int tok = mo * 16 + quad * 4 + r;
                if (tok < 49)
                    os[tok * 136 + h * 32 + nv * 16 + l16] = cvt_bf16_fast(oacc[mo][nv][r]);
            }
    __syncthreads();                       // barrier: os complete, all waves read all cols

    // ---------------- Stage 4: out = O @ W_proj + b_proj (kk-outer) ----------------
    f32x4 pacc[2][4];
    #pragma unroll
    for (int ct = 0; ct < 2; ++ct)
        #pragma unroll
        for (int mi = 0; mi < 4; ++mi) pacc[ct][mi] = fzero;
    #pragma unroll
    for (int kk = 0; kk < 4; ++kk) {
        bf16x8 ofrag[4];
        #pragma unroll
        for (int mi = 0; mi < 4; ++mi) {
            int row = mi * 16 + l16; if (row > 48) row = 48;
            ofrag[mi] = *(const bf16x8*)(os + row * 136 + kk * 32 + quad * 8);
        }
        #pragma unroll
        for (int ct = 0; ct < 2; ++ct) {
            const int c0 = (w * 2 + ct) * 16;
            bf16x8 wfrag = *(const bf16x8*)(wpt + (c0 + l16) * 128 + kk * 32 + quad * 8);
            #pragma unroll
            for (int mi = 0; mi < 4; ++mi)
                pacc[ct][mi] = __builtin_amdgcn_mfma_f32_16x16x32_bf16(ofrag[mi], wfrag, pacc[ct][mi], 0, 0, 0);
        }
    }
    #pragma unroll
    for (int ct = 0; ct < 2; ++ct) {
        const int c0 = (w * 2 + ct) * 16;
        const float bb = bpj[c0 + l16];
        #pragma unroll
        for (int mi = 0; mi < 4; ++mi)
            #pragma unroll
            for (int r = 0; r < 4; ++r) {
                int tok = mi * 16 + quad * 4 + r;
                if (tok < 49)
                    out[((long)b * 49 + tok) * 128 + c0 + l16] = pacc[ct][mi][r] + bb;
            }
    }
}

extern "C" void kernel_launch(void* const* d_in, const int* in_sizes, int n_in,
                              void* d_out, int out_size, void* d_ws, size_t ws_size,
                              hipStream_t stream) {
    const float* x    = (const float*)d_in[0];
    const float* qg   = (const float*)d_in[1];
    const float* rbt  = (const float*)d_in[2];
    const float* wkv  = (const float*)d_in[3];
    const float* bkv  = (const float*)d_in[4];
    const float* wpj  = (const float*)d_in[5];
    const float* bpj  = (const float*)d_in[6];
    const int*   ridx = (const int*)d_in[7];
    short* ws = (short*)d_ws;

    const int prep_total = 32768 + 16384 + 100352 + 12544;
    prep_kernel<<<(prep_total + 255) / 256, 256, 0, stream>>>(qg, rbt, wkv, wpj, ridx, ws);
    win_attn_kernel<<<4096, 256, 0, stream>>>(x, ws, bkv, bpj, (float*)d_out);
}

// Round 6
// 267.250 us; speedup vs baseline: 1.1085x; 1.1085x over previous
//
#include <hip/hip_runtime.h>

#define SCALE 0.17677669529663687f

typedef __attribute__((ext_vector_type(8))) short bf16x8;
typedef __attribute__((ext_vector_type(4))) short bf16x4;
typedef __attribute__((ext_vector_type(4))) float f32x4;

__device__ inline short cvt_bf16(float f) {          // RNE (prep: weights/q)
    union { float f; unsigned u; } v; v.f = f;
    unsigned r = v.u + 0x7fffu + ((v.u >> 16) & 1u);
    return (short)(r >> 16);
}
__device__ inline short cvt_bf16_fast(float f) {     // round-up-ties, 2 ops
    union { float f; unsigned u; } v; v.f = f;
    return (short)((v.u + 0x8000u) >> 16);
}
__device__ inline unsigned pack_bf16x2(float f0, float f1) {
    union { float f; unsigned u; } a, b; a.f = f0; b.f = f1;
    return __builtin_amdgcn_perm(b.u + 0x8000u, a.u + 0x8000u, 0x07060302u);
}

#if __has_builtin(__builtin_amdgcn_mfma_f32_16x16x16bf16_1k)
__device__ inline f32x4 mfma16x16(bf16x4 a, bf16x4 b, f32x4 c) {
    return __builtin_amdgcn_mfma_f32_16x16x16bf16_1k(a, b, c, 0, 0, 0);
}
#else
__device__ inline f32x4 mfma16x16(bf16x4 a, bf16x4 b, f32x4 c) {
    asm("v_mfma_f32_16x16x16_bf16 %0, %1, %2, %0" : "+v"(c) : "v"(a), "v"(b));
    return c;
}
#endif

// ws layout (short elements):
//   [0, 32768)        W_kv^T  bf16 [256][128]
//   [32768, 49152)    W_proj^T bf16 [128][128]
//   [49152, 450560)   q bf16 * SCALE, [64 img][4 h][49 n][32 d]
//   short 450560..    bias fp32 [4 h][49 i][64 jpad]  (pad = -3e38: j-mask baked in)
#define WS_WPT  32768
#define WS_QW   49152
#define WS_BIAS 450560

__global__ void prep_kernel(const float* __restrict__ qg,
                            const float* __restrict__ rbt,
                            const float* __restrict__ wkv,
                            const float* __restrict__ wpj,
                            const int*   __restrict__ ridx,
                            short* __restrict__ ws) {
    int i = blockIdx.x * 256 + threadIdx.x;
    if (i < 32768) {                       // W_kv^T: coalesced READ, scattered write
        int k = i >> 8, c = i & 255;       // (scattered reads stall; writes don't)
        ws[c * 128 + k] = cvt_bf16(wkv[i]);
        return;
    }
    i -= 32768;
    if (i < 16384) {                       // W_proj^T: coalesced read, scattered write
        int k = i >> 7, c = i & 127;
        ws[WS_WPT + c * 128 + k] = cvt_bf16(wpj[i]);
        return;
    }
    i -= 16384;
    if (i < 100352) {                      // q * SCALE, 4 elems/thread
        float4 q4 = *(const float4*)(qg + (long)i * 4);
        unsigned lo = (unsigned)(unsigned short)cvt_bf16(q4.x * SCALE) |
                      ((unsigned)(unsigned short)cvt_bf16(q4.y * SCALE) << 16);
        unsigned hi = (unsigned)(unsigned short)cvt_bf16(q4.z * SCALE) |
                      ((unsigned)(unsigned short)cvt_bf16(q4.w * SCALE) << 16);
        uint2 u; u.x = lo; u.y = hi;
        *(uint2*)(ws + WS_QW + (long)i * 4) = u;
        return;
    }
    i -= 100352;
    if (i < 12544) {                       // bias padded [h][i][64]; pad = -3e38 (mask)
        int h = i / 3136, rem = i % 3136, ir = rem >> 6, j = rem & 63;
        float* bias = (float*)(ws + WS_BIAS);
        bias[i] = (j < 49) ? rbt[ridx[ir * 49 + j] * 4 + h] : -3.0e38f;
    }
}

// LDS (shorts), 29008 B. Time-multiplexed regions (round-4 layout = best, 130us):
//  xs @0: x as bf16 [49][136]             -- stage 0/1
//  K  @6664: [4 heads][49 rows x 40]      -- own-wave written & read (no barrier)
//  os @0: [49][136]                       -- overlays xs after barrier 2
// V and P never touch LDS (reg-resident 16x16x16 B-frag / A-frag layouts).
// Stage 1 split K-pass/V-pass keeps per-stage live sets small.
// launch_bounds (256,4): the 5-wave budget (96 regs) force-spills (rounds 1/3:
// WRITE_SIZE 110->277..311 MB scratch) AND the HW VGPR granularity cliff at
// 64/128 makes 5 waves/SIMD unreachable anyway. Occupancy is fixed; this round
// cuts per-wave instructions + hoists loads across barriers instead.
#define KOFF    6664
#define KSLOT   1960
#define SMEM_SZ 14504

__global__ __launch_bounds__(256, 4) void win_attn_kernel(
        const float* __restrict__ x,
        const short* __restrict__ ws,
        const float* __restrict__ bkv,
        const float* __restrict__ bpj,
        float* __restrict__ out) {
    const int b    = blockIdx.x;
    const int img  = b >> 6;
    const int tid  = threadIdx.x;
    const int w    = tid >> 6;
    const int lane = tid & 63;
    const int quad = lane >> 4;
    const int l16  = lane & 15;

    const short* wkvt  = ws;
    const short* wpt   = ws + WS_WPT;
    const short* qw    = ws + WS_QW;
    const float* biasb = (const float*)(ws + WS_BIAS);

    __shared__ __align__(16) short smem[SMEM_SZ];
    short* xs = smem;
    short* os = smem;

    const f32x4 fzero = {0.f, 0.f, 0.f, 0.f};
    const int h = w;

    // ---------------- Stage 0: x -> bf16 -> LDS [49][136-stride] ----------------
    const float* xb = x + (long)b * 49 * 128;
    #pragma unroll
    for (int it = 0; it < 4; ++it) {
        int chunk = tid + it * 256;        // 784 chunks = 49 rows x 16 col8-groups
        if (chunk < 784) {
            int row = chunk >> 4, c8 = (chunk & 15) * 8;
            const float* p = xb + row * 128 + c8;
            float4 a = *(const float4*)p;
            float4 c = *(const float4*)(p + 4);
            union { uint4 u; bf16x8 v; } pk;
            pk.u.x = pack_bf16x2(a.x, a.y);
            pk.u.y = pack_bf16x2(a.z, a.w);
            pk.u.z = pack_bf16x2(c.x, c.y);
            pk.u.w = pack_bf16x2(c.z, c.w);
            *(bf16x8*)(xs + row * 136 + c8) = pk.v;
        }
    }
    // Preload stage-1A weight fragments BEFORE the barrier: their L2 latency
    // overlaps the staging drain + barrier wait (no data dependency).
    bf16x8 bfrk[4][2];
    #pragma unroll
    for (int kk = 0; kk < 4; ++kk)
        #pragma unroll
        for (int nt = 0; nt < 2; ++nt)
            bfrk[kk][nt] = *(const bf16x8*)(wkvt + (h * 32 + nt * 16 + l16) * 128 + kk * 32 + quad * 8);
    __syncthreads();                       // barrier 1: xs complete

    // ---------------- Stage 1A: K = x @ W_kv[:, h*32 .. h*32+32) ----------------
    short* ksl = smem + KOFF + h * KSLOT;
    {
        f32x4 acck[2][4];
        #pragma unroll
        for (int nt = 0; nt < 2; ++nt)
            #pragma unroll
            for (int mi = 0; mi < 4; ++mi) acck[nt][mi] = fzero;

        __builtin_amdgcn_s_setprio(1);
        #pragma unroll
        for (int kk = 0; kk < 4; ++kk) {
            #pragma unroll
            for (int mi = 0; mi < 4; ++mi) {
                int tok = mi * 16 + l16; if (tok > 48) tok = 48;
                bf16x8 af = *(const bf16x8*)(xs + tok * 136 + kk * 32 + quad * 8);
                #pragma unroll
                for (int nt = 0; nt < 2; ++nt)
                    acck[nt][mi] = __builtin_amdgcn_mfma_f32_16x16x32_bf16(af, bfrk[kk][nt], acck[nt][mi], 0, 0, 0);
            }
        }
        __builtin_amdgcn_s_setprio(0);
        // K -> LDS own-head slot (same-wave RW, disjoint region: no barrier)
        #pragma unroll
        for (int nt = 0; nt < 2; ++nt) {
            const int d = nt * 16 + l16;
            const float bv = bkv[h * 32 + d];
            short* kdst = ksl + d;
            #pragma unroll
            for (int mi = 0; mi < 4; ++mi)
                #pragma unroll
                for (int r = 0; r < 4; ++r) {
                    int tok = mi * 16 + quad * 4 + r;
                    if (tok < 49) kdst[tok * 40] = cvt_bf16_fast(acck[nt][mi][r] + bv);
                }
        }
    }

    // ---------------- Stage 1B: V = x @ W_kv[:, 128+h*32 ..) -> registers ----------------
    // acc layout (row=16*kt+4*quad+r, col=l16) == 16x16x16 MFMA B-fragment
    bf16x4 vfrag[2][4];                    // [nv][kt]
    {
        f32x4 accv[2][4];
        #pragma unroll
        for (int nv = 0; nv < 2; ++nv)
            #pragma unroll
            for (int mi = 0; mi < 4; ++mi) accv[nv][mi] = fzero;

        __builtin_amdgcn_s_setprio(1);
        #pragma unroll
        for (int kk = 0; kk < 4; ++kk) {
            bf16x8 bfr[2];
            #pragma unroll
            for (int nv = 0; nv < 2; ++nv)
                bfr[nv] = *(const bf16x8*)(wkvt + (128 + h * 32 + nv * 16 + l16) * 128 + kk * 32 + quad * 8);
            #pragma unroll
            for (int mi = 0; mi < 4; ++mi) {
                int tok = mi * 16 + l16; if (tok > 48) tok = 48;
                bf16x8 af = *(const bf16x8*)(xs + tok * 136 + kk * 32 + quad * 8);
                #pragma unroll
                for (int nv = 0; nv < 2; ++nv)
                    accv[nv][mi] = __builtin_amdgcn_mfma_f32_16x16x32_bf16(af, bfr[nv], accv[nv][mi], 0, 0, 0);
            }
        }
        __builtin_amdgcn_s_setprio(0);
        #pragma unroll
        for (int nv = 0; nv < 2; ++nv) {
            const float bv = bkv[128 + h * 32 + nv * 16 + l16];
            #pragma unroll
            for (int kt = 0; kt < 4; ++kt) {
                union { unsigned u[2]; bf16x4 v; } pk;
                pk.u[0] = pack_bf16x2(accv[nv][kt][0] + bv, accv[nv][kt][1] + bv);
                pk.u[1] = pack_bf16x2(accv[nv][kt][2] + bv, accv[nv][kt][3] + bv);
                vfrag[nv][kt] = pk.v;
            }
        }
    }

    // ---------------- Stage 2+3 fused: St = K@q^T, softmax, O += P@V ----------------
    // Hoisted invariants: qfr[4] (per-ni q frags), kfr[4] (ni-invariant K frags:
    // was re-read from LDS every ni = 12 wasted ds_read_b128).
    const short* qh = qw + (long)(img * 4 + h) * 49 * 32;
    bf16x8 qfr[4];
    #pragma unroll
    for (int ni = 0; ni < 4; ++ni) {
        int ic = ni * 16 + l16; if (ic > 48) ic = 48;
        qfr[ni] = *(const bf16x8*)(qh + ic * 32 + quad * 8);
    }
    bf16x8 kfr[4];
    #pragma unroll
    for (int mi = 0; mi < 4; ++mi) {
        int kr = mi * 16 + l16; if (kr > 48) kr = 48;
        kfr[mi] = *(const bf16x8*)(ksl + kr * 40 + quad * 8);
    }

    f32x4 oacc[4][2];                      // [mo=ni][nv]
    #pragma unroll
    for (int mo = 0; mo < 4; ++mo)
        #pragma unroll
        for (int nv = 0; nv < 2; ++nv) oacc[mo][nv] = fzero;

    #pragma unroll
    for (int ni = 0; ni < 4; ++ni) {
        f32x4 sacc[4] = {fzero, fzero, fzero, fzero};
        __builtin_amdgcn_s_setprio(1);
        #pragma unroll
        for (int mi = 0; mi < 4; ++mi)
            sacc[mi] = __builtin_amdgcn_mfma_f32_16x16x32_bf16(kfr[mi], qfr[ni], sacc[mi], 0, 0, 0);
        __builtin_amdgcn_s_setprio(0);

        // bias add (j-mask baked into table: pad cols hold -3e38)
        int ic = ni * 16 + l16; if (ic > 48) ic = 48;
        const float* bp = biasb + (h * 49 + ic) * 64;
        #pragma unroll
        for (int mi = 0; mi < 4; ++mi) {
            float4 b4 = *(const float4*)(bp + mi * 16 + quad * 4);
            sacc[mi][0] += b4.x; sacc[mi][1] += b4.y;
            sacc[mi][2] += b4.z; sacc[mi][3] += b4.w;
        }
        // max: shallow tree (max3-fusable triples), depth ~4 vs 15
        float mm[4];
        #pragma unroll
        for (int mi = 0; mi < 4; ++mi)
            mm[mi] = fmaxf(fmaxf(fmaxf(sacc[mi][0], sacc[mi][1]), sacc[mi][2]), sacc[mi][3]);
        float m = fmaxf(fmaxf(mm[0], mm[1]), fmaxf(mm[2], mm[3]));
        m = fmaxf(m, __shfl_xor(m, 16, 64));
        m = fmaxf(m, __shfl_xor(m, 32, 64));
        // exp + pairwise-tree sum (fp adds don't reassociate: tree by hand)
        float ps[4];
        #pragma unroll
        for (int mi = 0; mi < 4; ++mi) {
            float e0 = __expf(sacc[mi][0] - m);
            float e1 = __expf(sacc[mi][1] - m);
            float e2 = __expf(sacc[mi][2] - m);
            float e3 = __expf(sacc[mi][3] - m);
            sacc[mi][0] = e0; sacc[mi][1] = e1; sacc[mi][2] = e2; sacc[mi][3] = e3;
            ps[mi] = (e0 + e1) + (e2 + e3);
        }
        float sum = (ps[0] + ps[1]) + (ps[2] + ps[3]);
        sum += __shfl_xor(sum, 16, 64);
        sum += __shfl_xor(sum, 32, 64);
        float inv = 1.0f / sum;
        // P row is lane-local in 16x16x16 A-frag layout (k = quad*4+e): PV directly
        __builtin_amdgcn_s_setprio(1);
        #pragma unroll
        for (int kt = 0; kt < 4; ++kt) {
            union { unsigned u[2]; bf16x4 v; } pk;
            pk.u[0] = pack_bf16x2(sacc[kt][0] * inv, sacc[kt][1] * inv);
            pk.u[1] = pack_bf16x2(sacc[kt][2] * inv, sacc[kt][3] * inv);
            #pragma unroll
            for (int nv = 0; nv < 2; ++nv)
                oacc[ni][nv] = mfma16x16(pk.v, vfrag[nv][kt], oacc[ni][nv]);
        }
        __builtin_amdgcn_s_setprio(0);
    }

    // Preload stage-4 weight fragments BEFORE the barrier (global, no os dep).
    bf16x8 wfragA[4][2];
    #pragma unroll
    for (int kk = 0; kk < 4; ++kk)
        #pragma unroll
        for (int ct = 0; ct < 2; ++ct)
            wfragA[kk][ct] = *(const bf16x8*)(wpt + ((w * 2 + ct) * 16 + l16) * 128 + kk * 32 + quad * 8);

    __syncthreads();                       // barrier 2: all waves done with K/xs reads

    #pragma unroll
    for (int mo = 0; mo < 4; ++mo)
        #pragma unroll
        for (int nv = 0; nv < 2; ++nv)
            #pragma unroll
            for (int r = 0; r < 4; ++r) {
                int tok = mo * 16 + quad * 4 + r;
                os[tok * 136 + h * 32 + nv * 16 + l16] = cvt_bf16_fast(oacc[mo][nv][r]);
            }
    __syncthreads();                       // barrier 3: os complete

    // ---------------- Stage 4: out = O @ W_proj + b_proj (kk-outer) ----------------
    f32x4 pacc[2][4];
    #pragma unroll
    for (int ct = 0; ct < 2; ++ct)
        #pragma unroll
        for (int mi = 0; mi < 4; ++mi) pacc[ct][mi] = fzero;
    __builtin_amdgcn_s_setprio(1);
    #pragma unroll
    for (int kk = 0; kk < 4; ++kk) {
        bf16x8 ofrag[4];
        #pragma unroll
        for (int mi = 0; mi < 4; ++mi)
            ofrag[mi] = *(const bf16x8*)(os + (mi * 16 + l16) * 136 + kk * 32 + quad * 8);
        #pragma unroll
        for (int ct = 0; ct < 2; ++ct)
            #pragma unroll
            for (int mi = 0; mi < 4; ++mi)
                pacc[ct][mi] = __builtin_amdgcn_mfma_f32_16x16x32_bf16(ofrag[mi], wfragA[kk][ct], pacc[ct][mi], 0, 0, 0);
    }
    __builtin_amdgcn_s_setprio(0);
    #pragma unroll
    for (int ct = 0; ct < 2; ++ct) {
        const int c0 = (w * 2 + ct) * 16;
        const float bb = bpj[c0 + l16];
        #pragma unroll
        for (int mi = 0; mi < 4; ++mi)
            #pragma unroll
            for (int r = 0; r < 4; ++r) {
                int tok = mi * 16 + quad * 4 + r;
                if (tok < 49)
                    out[((long)b * 49 + tok) * 128 + c0 + l16] = pacc[ct][mi][r] + bb;
            }
    }
}

extern "C" void kernel_launch(void* const* d_in, const int* in_sizes, int n_in,
                              void* d_out, int out_size, void* d_ws, size_t ws_size,
                              hipStream_t stream) {
    const float* x    = (const float*)d_in[0];
    const float* qg   = (const float*)d_in[1];
    const float* rbt  = (const float*)d_in[2];
    const float* wkv  = (const float*)d_in[3];
    const float* bkv  = (const float*)d_in[4];
    const float* wpj  = (const float*)d_in[5];
    const float* bpj  = (const float*)d_in[6];
    const int*   ridx = (const int*)d_in[7];
    short* ws = (short*)d_ws;

    const int prep_total = 32768 + 16384 + 100352 + 12544;
    prep_kernel<<<(prep_total + 255) / 256, 256, 0, stream>>>(qg, rbt, wkv, wpj, ridx, ws);
    win_attn_kernel<<<4096, 256, 0, stream>>>(x, ws, bkv, bpj, (float*)d_out);
}